// Round 2
// baseline (624.119 us; speedup 1.0000x reference)
//
#include <hip/hip_runtime.h>
#include <hip/hip_bf16.h>
#include <math.h>

#define N_NODES 50000
#define N_EDGES 800000
#define EP_PAD  1150000   /* worst-case padded edges: 800000 + 50000*7 */
#define DIM 256
#define MPAD 50176   /* 196 gemm blocks * 256 rows; 1568 tiles of 32 rows */
#define LN_EPS 1e-5f
#define SCAN_BLOCKS 196  /* 196*256 = 50176 >= N_NODES */

typedef short bf16x8 __attribute__((ext_vector_type(8)));
typedef float f32x16 __attribute__((ext_vector_type(16)));
typedef unsigned short u16;
typedef u16 u16x8 __attribute__((ext_vector_type(8)));

__device__ __forceinline__ u16 f2bf(float f) {
    union { float f; unsigned u; } v; v.f = f;
    unsigned r = (v.u + 0x7FFFu + ((v.u >> 16) & 1u)) >> 16;
    return (u16)r;
}
__device__ __forceinline__ float bf2f(u16 h) {
    union { unsigned u; float f; } v; v.u = ((unsigned)h) << 16;
    return v.f;
}
// tanh-form gelu via sigmoid: max |err| vs exact ~3e-3, inside tolerance.
__device__ __forceinline__ float gelu_f(float x) {
    float z = x * (1.595769122f + 0.0713548162726f * x * x);
    return x * (1.0f / (1.0f + __expf(-z)));
}

// ---------------- CSR build (degree padded to multiple of 8) ----------------
__global__ void count_kernel(const int* __restrict__ dst, int* __restrict__ counts) {
    int e = blockIdx.x * 256 + threadIdx.x;
    if (e < N_EDGES) atomicAdd(&counts[dst[e]], 1);
}

__global__ void scan1_kernel(const int* __restrict__ counts, int* __restrict__ offsets,
                             int* __restrict__ bsum) {
    __shared__ int sh[256];
    int t = threadIdx.x;
    int idx = blockIdx.x * 256 + t;
    int v = (idx < N_NODES) ? ((counts[idx] + 7) & ~7) : 0;  // padded degree
    sh[t] = v;
    __syncthreads();
#pragma unroll
    for (int off = 1; off < 256; off <<= 1) {
        int u = (t >= off) ? sh[t - off] : 0;
        __syncthreads();
        sh[t] += u;
        __syncthreads();
    }
    if (idx < N_NODES) offsets[idx] = sh[t] - v;
    if (t == 255) bsum[blockIdx.x] = sh[255];
}

__global__ void scan2_kernel(const int* __restrict__ bsum, int* __restrict__ bbase) {
    __shared__ int sh[256];
    int t = threadIdx.x;
    int v = (t < SCAN_BLOCKS) ? bsum[t] : 0;
    sh[t] = v;
    __syncthreads();
#pragma unroll
    for (int off = 1; off < 256; off <<= 1) {
        int u = (t >= off) ? sh[t - off] : 0;
        __syncthreads();
        sh[t] += u;
        __syncthreads();
    }
    if (t < SCAN_BLOCKS) bbase[t] = sh[t] - v;
}

__global__ void scan3_kernel(int* __restrict__ offsets, const int* __restrict__ bbase,
                             const int* __restrict__ counts, int* __restrict__ cursor) {
    int idx = blockIdx.x * 256 + threadIdx.x;
    if (idx < N_NODES) {
        int o = offsets[idx] + bbase[blockIdx.x];
        offsets[idx] = o;
        cursor[idx] = o;
        if (idx == N_NODES - 1) offsets[N_NODES] = o + ((counts[idx] + 7) & ~7);
    }
}

__global__ void scatter_kernel(const int* __restrict__ src, const int* __restrict__ dst,
                               const float* __restrict__ w, int* __restrict__ cursor,
                               int2* __restrict__ ep) {
    int e = blockIdx.x * 256 + threadIdx.x;
    if (e < N_EDGES) {
        int d = dst[e];
        int p = atomicAdd(&cursor[d], 1);
        int2 v; v.x = src[e]; v.y = __float_as_int(w[e]);
        ep[p] = v;
    }
    // padded slots stay (src=0, w=0) from the memset: w*row0 == 0, row 0 is L1-hot
}

// ---------------- f32 -> bf16 row conversion (row-major out) ----------------
__global__ void conv_kernel(const float* __restrict__ in, u16* __restrict__ out) {
    int i = blockIdx.x * 256 + threadIdx.x;
    float4 v = ((const float4*)in)[i];
    ushort4 o;
    o.x = f2bf(v.x); o.y = f2bf(v.y); o.z = f2bf(v.z); o.w = f2bf(v.w);
    ((ushort4*)out)[i] = o;
}

// ---------------- weight transpose + bf16 convert ----------------
// WT[m][n][k] = bf16(W_m[k][n]);  m in {0:W1, 1:W2, 2:Wp}
__global__ void convw_kernel(const float* __restrict__ W1, const float* __restrict__ W2,
                             const float* __restrict__ Wp, u16* __restrict__ WT) {
    int idx = blockIdx.x * 256 + threadIdx.x;
    int m = idx >> 16;
    int r = idx & 65535;
    int n = r >> 8, k = r & 255;
    const float* W = (m == 0) ? W1 : (m == 1) ? W2 : Wp;
    WT[idx] = f2bf(W[k * 256 + n]);
}

// ---------------- SPMM v3: y = x + gather-sum; LDS-coalesced tiled-32 out ----
// Block = 32-node tile, 4 waves x 8 nodes. Wave split in two 32-lane halves,
// 16B/lane row loads. CSR segments padded to multiples of 8 -> branch-free
// inner loop, 8 edges/wave/iter (8 x 512B rows in flight), pads hit L1 row 0.
// Results staged through LDS so the tiled-32 granule write is fully coalesced
// (full 64B lines -> no write amplification; v2's direct stores cost 2.5x).
__global__ __launch_bounds__(256) void spmm_kernel(
        const u16* __restrict__ x, const int* __restrict__ offs,
        const int2* __restrict__ ep, u16* __restrict__ y) {
    __shared__ u16 tile[32 * 264];  // padded rows: 16.9 KB
    int tid = threadIdx.x;
    int wave = tid >> 6;
    int lane = tid & 63;
    int l31 = lane & 31, half = lane >> 5;
    int node0 = blockIdx.x * 32 + wave * 8;

    const u16x8* xv = (const u16x8*)x;
#pragma unroll 1
    for (int i = 0; i < 8; ++i) {
        int node = node0 + i;
        float acc[8];
#pragma unroll
        for (int j = 0; j < 8; ++j) acc[j] = 0.f;
        if (node < N_NODES) {
            if (half == 0) {
                u16x8 sv = xv[(size_t)node * 32 + l31];
#pragma unroll
                for (int j = 0; j < 8; ++j) acc[j] = bf2f(sv[j]);
            }
            int p  = offs[node] + half * 2;   // halves interleave 2-edge chunks
            int p1 = offs[node + 1];
            for (; p < p1; p += 8) {
                int4 ea = *(const int4*)&ep[p];       // edges p, p+1
                int4 eb = *(const int4*)&ep[p + 4];   // edges p+4, p+5
                int s0 = ea.x; float w0 = __int_as_float(ea.y);
                int s1 = ea.z; float w1 = __int_as_float(ea.w);
                int s2 = eb.x; float w2 = __int_as_float(eb.y);
                int s3 = eb.z; float w3 = __int_as_float(eb.w);
                u16x8 v0 = xv[(size_t)s0 * 32 + l31];
                u16x8 v1 = xv[(size_t)s1 * 32 + l31];
                u16x8 v2 = xv[(size_t)s2 * 32 + l31];
                u16x8 v3 = xv[(size_t)s3 * 32 + l31];
#pragma unroll
                for (int j = 0; j < 8; ++j) acc[j] += w0 * bf2f(v0[j]);
#pragma unroll
                for (int j = 0; j < 8; ++j) acc[j] += w1 * bf2f(v1[j]);
#pragma unroll
                for (int j = 0; j < 8; ++j) acc[j] += w2 * bf2f(v2[j]);
#pragma unroll
                for (int j = 0; j < 8; ++j) acc[j] += w3 * bf2f(v3[j]);
            }
        }
        // combine halves: lanes l, l+32 hold the same 8 dims for disjoint edges
#pragma unroll
        for (int j = 0; j < 8; ++j) acc[j] += __shfl_xor(acc[j], 32);
        if (half == 0) {
            u16x8 o;
#pragma unroll
            for (int j = 0; j < 8; ++j) o[j] = f2bf(acc[j]);
            *(u16x8*)&tile[(wave * 8 + i) * 264 + l31 * 8] = o;
        }
    }
    __syncthreads();
    // write tile in 32x32x16 A-fragment granule order: 1024 granules, 4/thread
    u16* outb = y + (size_t)blockIdx.x * 8192;
#pragma unroll
    for (int hh = 0; hh < 4; ++hh) {
        int gi = tid + hh * 256;
        int kb = gi >> 6;
        int rem = gi & 63;
        int hf = rem >> 5, m = rem & 31;
        u16x8 v = *(const u16x8*)&tile[m * 264 + kb * 16 + hf * 8];
        *(u16x8*)(outb + (size_t)gi * 8) = v;
    }
}

// ---------------- GEMM v3: 32x32x16 MFMA, fragment-tiled LDS B ----------------
// 256 rows/block (4 waves x 2 row-tiles of 32), grid 196, 1 block/CU.
// A tiled-32: A-frag = one contiguous 16B/lane load at tile*8192 + kb*512 + lane*8.
// B staged to LDS in fragment granules, group (t,kb) = 64 granules (1024B) + 16B
// pad (stride 520 u16) -> both staging writes and ds_read_b128 are 8-words/bank
// balanced. Per kb: 2 A-loads (prefetched) + 8 ds_read_b128 + 16 MFMA.
// MODE 0: out = bf16(gelu(LN(A@B+bias))), OUT_TILED: 0=row-major, 1=tiled-32.
// MODE 1: f_out = A@B + bias (f32 row-major, guarded).
template <int MODE, int OUT_TILED>
__global__ __launch_bounds__(256, 1) void gemm_kernel(
        const u16* __restrict__ A, const u16* __restrict__ BT,
        const float* __restrict__ bias, const float* __restrict__ g,
        const float* __restrict__ be, u16* __restrict__ xb_out,
        float* __restrict__ f_out) {
    __shared__ u16 b_lds[128 * 520];  // 133120 B
    int tid = threadIdx.x;
    int wave = tid >> 6, lane = tid & 63;
    int l31 = lane & 31, half = lane >> 5;

    // ---- stage B: 8192 16B-chunks, coalesced reads, granule-scatter writes ----
#pragma unroll 8
    for (int i = 0; i < 32; ++i) {
        int s = i * 256 + tid;
        u16x8 v = *(const u16x8*)(BT + (size_t)s * 8);
        int n = s >> 5, kc = s & 31;
        int t = n >> 5, n32 = n & 31, kb = kc >> 1, hf = kc & 1;
        *(u16x8*)&b_lds[(t * 16 + kb) * 520 + hf * 256 + n32 * 8] = v;
    }

    int tile0 = blockIdx.x * 8 + wave * 2;
    const u16* ga0 = A + (size_t)tile0 * 8192 + lane * 8;
    const u16* ga1 = ga0 + 8192;
    bf16x8 p0 = *(const bf16x8*)ga0;
    bf16x8 p1 = *(const bf16x8*)ga1;

    f32x16 acc[2][8];
#pragma unroll
    for (int rf = 0; rf < 2; ++rf)
#pragma unroll
        for (int t = 0; t < 8; ++t)
#pragma unroll
            for (int r = 0; r < 16; ++r) acc[rf][t][r] = 0.f;

    __syncthreads();

#pragma unroll
    for (int kb = 0; kb < 16; ++kb) {
        bf16x8 a0 = p0, a1 = p1;
        if (kb < 15) {
            p0 = *(const bf16x8*)(ga0 + (kb + 1) * 512);
            p1 = *(const bf16x8*)(ga1 + (kb + 1) * 512);
        }
        const u16* bl = &b_lds[kb * 520 + lane * 8];
#pragma unroll
        for (int t = 0; t < 8; ++t) {
            bf16x8 bf = *(const bf16x8*)(bl + t * 16 * 520);
            acc[0][t] = __builtin_amdgcn_mfma_f32_32x32x16_bf16(a0, bf, acc[0][t], 0, 0, 0);
            acc[1][t] = __builtin_amdgcn_mfma_f32_32x32x16_bf16(a1, bf, acc[1][t], 0, 0, 0);
        }
    }

    // ---- epilogue ----
    float bv[8];
#pragma unroll
    for (int t = 0; t < 8; ++t) bv[t] = bias[t * 32 + l31];

#pragma unroll
    for (int rf = 0; rf < 2; ++rf) {
        int tile = tile0 + rf;
        if (MODE == 0) {
            float gv[8], bev[8];
#pragma unroll
            for (int t = 0; t < 8; ++t) {
                int c = t * 32 + l31;
                gv[t] = g[c]; bev[t] = be[c];
            }
#pragma unroll
            for (int r = 0; r < 16; ++r) {
                float s = 0.f, q = 0.f;
#pragma unroll
                for (int t = 0; t < 8; ++t) {
                    float v = acc[rf][t][r] + bv[t];
                    acc[rf][t][r] = v;
                    s += v; q += v * v;
                }
                for (int off = 1; off < 32; off <<= 1) {
                    s += __shfl_xor(s, off);
                    q += __shfl_xor(q, off);
                }
                float mu = s * (1.0f / 256.0f);
                float var = q * (1.0f / 256.0f) - mu * mu;
                float rs = rsqrtf(var + LN_EPS);
                int m = (r & 3) + 8 * (r >> 2) + 4 * half;
                int row = tile * 32 + m;
#pragma unroll
                for (int t = 0; t < 8; ++t) {
                    int c = t * 32 + l31;
                    float v = (acc[rf][t][r] - mu) * rs * gv[t] + bev[t];
                    u16 ob = f2bf(gelu_f(v));
                    if (OUT_TILED) {
                        size_t o = (size_t)tile * 8192 +
                                   ((size_t)(c >> 4) * 64 + ((c >> 3) & 1) * 32 + m) * 8 + (c & 7);
                        xb_out[o] = ob;
                    } else {
                        xb_out[(size_t)row * 256 + c] = ob;
                    }
                }
            }
        } else {
#pragma unroll
            for (int r = 0; r < 16; ++r) {
                int m = (r & 3) + 8 * (r >> 2) + 4 * half;
                int row = tile * 32 + m;
                if (row < N_NODES) {
#pragma unroll
                    for (int t = 0; t < 8; ++t) {
                        int c = t * 32 + l31;
                        f_out[(size_t)row * 256 + c] = acc[rf][t][r] + bv[t];
                    }
                }
            }
        }
    }
}

extern "C" void kernel_launch(void* const* d_in, const int* in_sizes, int n_in,
                              void* d_out, int out_size, void* d_ws, size_t ws_size,
                              hipStream_t stream) {
    const float* nodef = (const float*)d_in[0];
    const int*   src   = (const int*)d_in[1];
    const int*   dst   = (const int*)d_in[2];
    const float* ew    = (const float*)d_in[3];
    const float* W1 = (const float*)d_in[4];
    const float* b1 = (const float*)d_in[5];
    const float* g1 = (const float*)d_in[6];
    const float* be1 = (const float*)d_in[7];
    const float* W2 = (const float*)d_in[8];
    const float* b2 = (const float*)d_in[9];
    const float* g2 = (const float*)d_in[10];
    const float* be2 = (const float*)d_in[11];
    const float* Wp = (const float*)d_in[12];
    const float* bp = (const float*)d_in[13];
    float* out = (float*)d_out;

    char* ws = (char*)d_ws;
    size_t off = 0;
    auto alloc = [&](size_t bytes) -> void* {
        void* p = ws + off;
        off += (bytes + 255) & ~(size_t)255;
        return p;
    };
    u16*   ybuf    = (u16*)alloc((size_t)MPAD * 256 * 2);  // tiled-32 activations
    u16*   xbuf    = (u16*)alloc((size_t)MPAD * 256 * 2);  // row-major activations
    u16*   WT      = (u16*)alloc((size_t)3 * 65536 * 2);
    int*   counts  = (int*)alloc((size_t)N_NODES * 4);
    int*   offsets = (int*)alloc((size_t)(N_NODES + 1) * 4);
    int*   cursor  = (int*)alloc((size_t)N_NODES * 4);
    int2*  ep      = (int2*)alloc((size_t)EP_PAD * 8);
    int*   bsum    = (int*)alloc((size_t)SCAN_BLOCKS * 4);
    int*   bbase   = (int*)alloc((size_t)SCAN_BLOCKS * 4);

    hipMemsetAsync(counts, 0, (size_t)N_NODES * 4, stream);
    hipMemsetAsync(ep, 0, (size_t)EP_PAD * 8, stream);  // pad edges = (src 0, w 0)
    count_kernel<<<(N_EDGES + 255) / 256, 256, 0, stream>>>(dst, counts);
    scan1_kernel<<<SCAN_BLOCKS, 256, 0, stream>>>(counts, offsets, bsum);
    scan2_kernel<<<1, 256, 0, stream>>>(bsum, bbase);
    scan3_kernel<<<SCAN_BLOCKS, 256, 0, stream>>>(offsets, bbase, counts, cursor);
    scatter_kernel<<<(N_EDGES + 255) / 256, 256, 0, stream>>>(src, dst, ew, cursor, ep);
    conv_kernel<<<N_NODES * 64 / 256, 256, 0, stream>>>(nodef, xbuf);
    convw_kernel<<<768, 256, 0, stream>>>(W1, W2, Wp, WT);

    const int GB = MPAD / 256;   // 196 gemm blocks
    const int SB = MPAD / 32;    // 1568 spmm tile-blocks (covers all gemm tiles)
    // layer 1: gather xbuf(row-major) -> ybuf(tiled-32); gemm -> xbuf(row-major)
    spmm_kernel<<<SB, 256, 0, stream>>>(xbuf, offsets, ep, ybuf);
    gemm_kernel<0, 0><<<GB, 256, 0, stream>>>(ybuf, WT, b1, g1, be1, xbuf, nullptr);
    // layer 2: gather xbuf -> ybuf(tiled-32); gemm -> ybuf IN-PLACE (tiled-32)
    spmm_kernel<<<SB, 256, 0, stream>>>(xbuf, offsets, ep, ybuf);
    gemm_kernel<0, 1><<<GB, 256, 0, stream>>>(ybuf, WT + 65536, b2, g2, be2, ybuf, nullptr);
    // projection: tiled-32 A -> f32 row-major out
    gemm_kernel<1, 0><<<GB, 256, 0, stream>>>(ybuf, WT + 2 * 65536, bp, nullptr, nullptr, nullptr, out);
}

// Round 3
// 442.576 us; speedup vs baseline: 1.4102x; 1.4102x over previous
//
#include <hip/hip_runtime.h>
#include <hip/hip_bf16.h>
#include <math.h>

#define N_NODES 50000
#define N_EDGES 800000
#define DIM 256
#define MPAD 50176   /* 196 gemm blocks * 256 rows; 1568 tiles of 32 rows */
#define LN_EPS 1e-5f
#define SCAN_BLOCKS 196  /* 196*256 = 50176 >= N_NODES */

typedef short bf16x8 __attribute__((ext_vector_type(8)));
typedef float f32x16 __attribute__((ext_vector_type(16)));
typedef unsigned short u16;
typedef u16 u16x8 __attribute__((ext_vector_type(8)));

__device__ __forceinline__ u16 f2bf(float f) {
    union { float f; unsigned u; } v; v.f = f;
    unsigned r = (v.u + 0x7FFFu + ((v.u >> 16) & 1u)) >> 16;
    return (u16)r;
}
__device__ __forceinline__ float bf2f(u16 h) {
    union { unsigned u; float f; } v; v.u = ((unsigned)h) << 16;
    return v.f;
}
// tanh-form gelu via sigmoid: max |err| vs exact ~3e-3, inside tolerance.
__device__ __forceinline__ float gelu_f(float x) {
    float z = x * (1.595769122f + 0.0713548162726f * x * x);
    return x * (1.0f / (1.0f + __expf(-z)));
}

// ---------------- CSR build ----------------
__global__ void count_kernel(const int* __restrict__ dst, int* __restrict__ counts) {
    int e = blockIdx.x * 256 + threadIdx.x;
    if (e < N_EDGES) atomicAdd(&counts[dst[e]], 1);
}

__global__ void scan1_kernel(const int* __restrict__ counts, int* __restrict__ offsets,
                             int* __restrict__ bsum) {
    __shared__ int sh[256];
    int t = threadIdx.x;
    int idx = blockIdx.x * 256 + t;
    int v = (idx < N_NODES) ? counts[idx] : 0;
    sh[t] = v;
    __syncthreads();
#pragma unroll
    for (int off = 1; off < 256; off <<= 1) {
        int u = (t >= off) ? sh[t - off] : 0;
        __syncthreads();
        sh[t] += u;
        __syncthreads();
    }
    if (idx < N_NODES) offsets[idx] = sh[t] - v;
    if (t == 255) bsum[blockIdx.x] = sh[255];
}

__global__ void scan2_kernel(const int* __restrict__ bsum, int* __restrict__ bbase) {
    __shared__ int sh[256];
    int t = threadIdx.x;
    int v = (t < SCAN_BLOCKS) ? bsum[t] : 0;
    sh[t] = v;
    __syncthreads();
#pragma unroll
    for (int off = 1; off < 256; off <<= 1) {
        int u = (t >= off) ? sh[t - off] : 0;
        __syncthreads();
        sh[t] += u;
        __syncthreads();
    }
    if (t < SCAN_BLOCKS) bbase[t] = sh[t] - v;
}

__global__ void scan3_kernel(int* __restrict__ offsets, const int* __restrict__ bbase,
                             int* __restrict__ cursor) {
    int idx = blockIdx.x * 256 + threadIdx.x;
    if (idx < N_NODES) {
        int o = offsets[idx] + bbase[blockIdx.x];
        offsets[idx] = o;
        cursor[idx] = o;
    }
    if (idx == 0) offsets[N_NODES] = N_EDGES;
}

__global__ void scatter_kernel(const int* __restrict__ src, const int* __restrict__ dst,
                               const float* __restrict__ w, int* __restrict__ cursor,
                               int2* __restrict__ ep) {
    int e = blockIdx.x * 256 + threadIdx.x;
    if (e < N_EDGES) {
        int d = dst[e];
        int p = atomicAdd(&cursor[d], 1);
        int2 v; v.x = src[e]; v.y = __float_as_int(w[e]);
        ep[p] = v;
    }
}

// ---------------- f32 -> bf16 row conversion (row-major out) ----------------
__global__ void conv_kernel(const float* __restrict__ in, u16* __restrict__ out) {
    int i = blockIdx.x * 256 + threadIdx.x;
    float4 v = ((const float4*)in)[i];
    ushort4 o;
    o.x = f2bf(v.x); o.y = f2bf(v.y); o.z = f2bf(v.z); o.w = f2bf(v.w);
    ((ushort4*)out)[i] = o;
}

// ---------------- weight transpose + bf16 convert ----------------
// WT[m][n][k] = bf16(W_m[k][n]);  m in {0:W1, 1:W2, 2:Wp}
__global__ void convw_kernel(const float* __restrict__ W1, const float* __restrict__ W2,
                             const float* __restrict__ Wp, u16* __restrict__ WT) {
    int idx = blockIdx.x * 256 + threadIdx.x;
    int m = idx >> 16;
    int r = idx & 65535;
    int n = r >> 8, k = r & 255;
    const float* W = (m == 0) ? W1 : (m == 1) ? W2 : Wp;
    WT[idx] = f2bf(W[k * 256 + n]);
}

// ---------------- SPMM: y = x + gather-sum; TILED-32 bf16 output ----------------
// Block = one 32-row tile, 4 waves x 8 nodes. Gather input x is ROW-major bf16.
// Structure identical to the 449.6us round-0 baseline; only change: edge index
// and weight are fused into one int2 array (ep) so the per-edge descriptor is
// one 8B load instead of two dependent 4B loads. Loads stay wave-uniform.
// Output layout (matches mfma_32x32x16 A-fragment): tile T, granule
// gi = kb*64 + half*32 + m  (kb in 0..15, half = k-half, m = row in tile)
// at T*8192 + gi*8 holds row m, k = kb*16 + half*8 .. +8.
__global__ __launch_bounds__(256) void spmm_kernel(
        const u16* __restrict__ x, const int* __restrict__ offs,
        const int2* __restrict__ ep, u16* __restrict__ y) {
    __shared__ u16 tile[32 * 264];  // padded rows: 16.9 KB
    int tid = threadIdx.x;
    int wave = tid >> 6;
    int lane = tid & 63;
    int node0 = blockIdx.x * 32 + wave * 8;

    const ushort4* xv = (const ushort4*)x;
#pragma unroll 1
    for (int i = 0; i < 8; ++i) {
        int node = node0 + i;
        float a0 = 0, a1 = 0, a2 = 0, a3 = 0;
        float b0 = 0, b1 = 0, b2 = 0, b3 = 0;
        float c0 = 0, c1 = 0, c2 = 0, c3 = 0;
        float d0 = 0, d1 = 0, d2 = 0, d3 = 0;
        if (node < N_NODES) {
            ushort4 v = xv[(size_t)node * 64 + lane];
            a0 = bf2f(v.x); a1 = bf2f(v.y); a2 = bf2f(v.z); a3 = bf2f(v.w);
            int p = offs[node];
            int p1 = offs[node + 1];
            for (; p + 4 <= p1; p += 4) {
                int2 e0 = ep[p],     e1 = ep[p + 1];
                int2 e2 = ep[p + 2], e3 = ep[p + 3];
                int s0 = e0.x; float w0 = __int_as_float(e0.y);
                int s1 = e1.x; float w1 = __int_as_float(e1.y);
                int s2 = e2.x; float w2 = __int_as_float(e2.y);
                int s3 = e3.x; float w3 = __int_as_float(e3.y);
                ushort4 v0 = xv[(size_t)s0 * 64 + lane];
                ushort4 v1 = xv[(size_t)s1 * 64 + lane];
                ushort4 v2 = xv[(size_t)s2 * 64 + lane];
                ushort4 v3 = xv[(size_t)s3 * 64 + lane];
                a0 += w0 * bf2f(v0.x); a1 += w0 * bf2f(v0.y); a2 += w0 * bf2f(v0.z); a3 += w0 * bf2f(v0.w);
                b0 += w1 * bf2f(v1.x); b1 += w1 * bf2f(v1.y); b2 += w1 * bf2f(v1.z); b3 += w1 * bf2f(v1.w);
                c0 += w2 * bf2f(v2.x); c1 += w2 * bf2f(v2.y); c2 += w2 * bf2f(v2.z); c3 += w2 * bf2f(v2.w);
                d0 += w3 * bf2f(v3.x); d1 += w3 * bf2f(v3.y); d2 += w3 * bf2f(v3.z); d3 += w3 * bf2f(v3.w);
            }
            for (; p < p1; ++p) {
                int2 e = ep[p];
                int s = e.x;
                float w = __int_as_float(e.y);
                ushort4 vv = xv[(size_t)s * 64 + lane];
                a0 += w * bf2f(vv.x); a1 += w * bf2f(vv.y); a2 += w * bf2f(vv.z); a3 += w * bf2f(vv.w);
            }
            a0 += b0 + c0 + d0; a1 += b1 + c1 + d1;
            a2 += b2 + c2 + d2; a3 += b3 + c3 + d3;
        }
        ushort4 o;
        o.x = f2bf(a0); o.y = f2bf(a1); o.z = f2bf(a2); o.w = f2bf(a3);
        ((ushort4*)&tile[(wave * 8 + i) * 264])[lane] = o;
    }
    __syncthreads();
    // write tile in 32x32x16 A-fragment granule order: 1024 granules, 4/thread
    u16* outb = y + (size_t)blockIdx.x * 8192;
#pragma unroll
    for (int hh = 0; hh < 4; ++hh) {
        int gi = tid + hh * 256;
        int kb = gi >> 6;
        int rem = gi & 63;
        int hf = rem >> 5, m = rem & 31;
        u16x8 v = *(const u16x8*)&tile[m * 264 + kb * 16 + hf * 8];
        *(u16x8*)(outb + (size_t)gi * 8) = v;
    }
}

// ---------------- GEMM v3: 32x32x16 MFMA, fragment-tiled LDS B ----------------
// 256 rows/block (4 waves x 2 row-tiles of 32), grid 196, 1 block/CU.
// A tiled-32: A-frag = one contiguous 16B/lane load at tile*8192 + kb*512 + lane*8.
// B staged to LDS in fragment granules, group (t,kb) = 64 granules (1024B) + 16B
// pad (stride 520 u16) -> both staging writes and ds_read_b128 are 8-words/bank
// balanced. Per kb: 2 A-loads (prefetched) + 8 ds_read_b128 + 16 MFMA.
// MODE 0: out = bf16(gelu(LN(A@B+bias))), OUT_TILED: 0=row-major, 1=tiled-32.
// MODE 1: f_out = A@B + bias (f32 row-major, guarded).
template <int MODE, int OUT_TILED>
__global__ __launch_bounds__(256, 1) void gemm_kernel(
        const u16* __restrict__ A, const u16* __restrict__ BT,
        const float* __restrict__ bias, const float* __restrict__ g,
        const float* __restrict__ be, u16* __restrict__ xb_out,
        float* __restrict__ f_out) {
    __shared__ u16 b_lds[128 * 520];  // 133120 B
    int tid = threadIdx.x;
    int wave = tid >> 6, lane = tid & 63;
    int l31 = lane & 31, half = lane >> 5;

    // ---- stage B: 8192 16B-chunks, coalesced reads, granule-scatter writes ----
#pragma unroll 8
    for (int i = 0; i < 32; ++i) {
        int s = i * 256 + tid;
        u16x8 v = *(const u16x8*)(BT + (size_t)s * 8);
        int n = s >> 5, kc = s & 31;
        int t = n >> 5, n32 = n & 31, kb = kc >> 1, hf = kc & 1;
        *(u16x8*)&b_lds[(t * 16 + kb) * 520 + hf * 256 + n32 * 8] = v;
    }

    int tile0 = blockIdx.x * 8 + wave * 2;
    const u16* ga0 = A + (size_t)tile0 * 8192 + lane * 8;
    const u16* ga1 = ga0 + 8192;
    bf16x8 p0 = *(const bf16x8*)ga0;
    bf16x8 p1 = *(const bf16x8*)ga1;

    f32x16 acc[2][8];
#pragma unroll
    for (int rf = 0; rf < 2; ++rf)
#pragma unroll
        for (int t = 0; t < 8; ++t)
#pragma unroll
            for (int r = 0; r < 16; ++r) acc[rf][t][r] = 0.f;

    __syncthreads();

#pragma unroll
    for (int kb = 0; kb < 16; ++kb) {
        bf16x8 a0 = p0, a1 = p1;
        if (kb < 15) {
            p0 = *(const bf16x8*)(ga0 + (kb + 1) * 512);
            p1 = *(const bf16x8*)(ga1 + (kb + 1) * 512);
        }
        const u16* bl = &b_lds[kb * 520 + lane * 8];
#pragma unroll
        for (int t = 0; t < 8; ++t) {
            bf16x8 bf = *(const bf16x8*)(bl + t * 16 * 520);
            acc[0][t] = __builtin_amdgcn_mfma_f32_32x32x16_bf16(a0, bf, acc[0][t], 0, 0, 0);
            acc[1][t] = __builtin_amdgcn_mfma_f32_32x32x16_bf16(a1, bf, acc[1][t], 0, 0, 0);
        }
    }

    // ---- epilogue ----
    float bv[8];
#pragma unroll
    for (int t = 0; t < 8; ++t) bv[t] = bias[t * 32 + l31];

#pragma unroll
    for (int rf = 0; rf < 2; ++rf) {
        int tile = tile0 + rf;
        if (MODE == 0) {
            float gv[8], bev[8];
#pragma unroll
            for (int t = 0; t < 8; ++t) {
                int c = t * 32 + l31;
                gv[t] = g[c]; bev[t] = be[c];
            }
#pragma unroll
            for (int r = 0; r < 16; ++r) {
                float s = 0.f, q = 0.f;
#pragma unroll
                for (int t = 0; t < 8; ++t) {
                    float v = acc[rf][t][r] + bv[t];
                    acc[rf][t][r] = v;
                    s += v; q += v * v;
                }
                for (int off = 1; off < 32; off <<= 1) {
                    s += __shfl_xor(s, off);
                    q += __shfl_xor(q, off);
                }
                float mu = s * (1.0f / 256.0f);
                float var = q * (1.0f / 256.0f) - mu * mu;
                float rs = rsqrtf(var + LN_EPS);
                int m = (r & 3) + 8 * (r >> 2) + 4 * half;
                int row = tile * 32 + m;
#pragma unroll
                for (int t = 0; t < 8; ++t) {
                    int c = t * 32 + l31;
                    float v = (acc[rf][t][r] - mu) * rs * gv[t] + bev[t];
                    u16 ob = f2bf(gelu_f(v));
                    if (OUT_TILED) {
                        size_t o = (size_t)tile * 8192 +
                                   ((size_t)(c >> 4) * 64 + ((c >> 3) & 1) * 32 + m) * 8 + (c & 7);
                        xb_out[o] = ob;
                    } else {
                        xb_out[(size_t)row * 256 + c] = ob;
                    }
                }
            }
        } else {
#pragma unroll
            for (int r = 0; r < 16; ++r) {
                int m = (r & 3) + 8 * (r >> 2) + 4 * half;
                int row = tile * 32 + m;
                if (row < N_NODES) {
#pragma unroll
                    for (int t = 0; t < 8; ++t) {
                        int c = t * 32 + l31;
                        f_out[(size_t)row * 256 + c] = acc[rf][t][r] + bv[t];
                    }
                }
            }
        }
    }
}

extern "C" void kernel_launch(void* const* d_in, const int* in_sizes, int n_in,
                              void* d_out, int out_size, void* d_ws, size_t ws_size,
                              hipStream_t stream) {
    const float* nodef = (const float*)d_in[0];
    const int*   src   = (const int*)d_in[1];
    const int*   dst   = (const int*)d_in[2];
    const float* ew    = (const float*)d_in[3];
    const float* W1 = (const float*)d_in[4];
    const float* b1 = (const float*)d_in[5];
    const float* g1 = (const float*)d_in[6];
    const float* be1 = (const float*)d_in[7];
    const float* W2 = (const float*)d_in[8];
    const float* b2 = (const float*)d_in[9];
    const float* g2 = (const float*)d_in[10];
    const float* be2 = (const float*)d_in[11];
    const float* Wp = (const float*)d_in[12];
    const float* bp = (const float*)d_in[13];
    float* out = (float*)d_out;

    char* ws = (char*)d_ws;
    size_t off = 0;
    auto alloc = [&](size_t bytes) -> void* {
        void* p = ws + off;
        off += (bytes + 255) & ~(size_t)255;
        return p;
    };
    u16*   ybuf    = (u16*)alloc((size_t)MPAD * 256 * 2);  // tiled-32 activations
    u16*   xbuf    = (u16*)alloc((size_t)MPAD * 256 * 2);  // row-major activations
    u16*   WT      = (u16*)alloc((size_t)3 * 65536 * 2);
    int*   counts  = (int*)alloc((size_t)N_NODES * 4);
    int*   offsets = (int*)alloc((size_t)(N_NODES + 1) * 4);
    int*   cursor  = (int*)alloc((size_t)N_NODES * 4);
    int2*  ep      = (int2*)alloc((size_t)N_EDGES * 8);
    int*   bsum    = (int*)alloc((size_t)SCAN_BLOCKS * 4);
    int*   bbase   = (int*)alloc((size_t)SCAN_BLOCKS * 4);

    hipMemsetAsync(counts, 0, (size_t)N_NODES * 4, stream);
    count_kernel<<<(N_EDGES + 255) / 256, 256, 0, stream>>>(dst, counts);
    scan1_kernel<<<SCAN_BLOCKS, 256, 0, stream>>>(counts, offsets, bsum);
    scan2_kernel<<<1, 256, 0, stream>>>(bsum, bbase);
    scan3_kernel<<<SCAN_BLOCKS, 256, 0, stream>>>(offsets, bbase, cursor);
    scatter_kernel<<<(N_EDGES + 255) / 256, 256, 0, stream>>>(src, dst, ew, cursor, ep);
    conv_kernel<<<N_NODES * 64 / 256, 256, 0, stream>>>(nodef, xbuf);
    convw_kernel<<<768, 256, 0, stream>>>(W1, W2, Wp, WT);

    const int GB = MPAD / 256;   // 196 gemm blocks
    const int SB = MPAD / 32;    // 1568 spmm tile-blocks (covers all gemm tiles)
    // layer 1: gather xbuf(row-major) -> ybuf(tiled-32); gemm -> xbuf(row-major)
    spmm_kernel<<<SB, 256, 0, stream>>>(xbuf, offsets, ep, ybuf);
    gemm_kernel<0, 0><<<GB, 256, 0, stream>>>(ybuf, WT, b1, g1, be1, xbuf, nullptr);
    // layer 2: gather xbuf -> ybuf(tiled-32); gemm -> ybuf IN-PLACE (tiled-32)
    spmm_kernel<<<SB, 256, 0, stream>>>(xbuf, offsets, ep, ybuf);
    gemm_kernel<0, 1><<<GB, 256, 0, stream>>>(ybuf, WT + 65536, b2, g2, be2, ybuf, nullptr);
    // projection: tiled-32 A -> f32 row-major out
    gemm_kernel<1, 0><<<GB, 256, 0, stream>>>(ybuf, WT + 2 * 65536, bp, nullptr, nullptr, nullptr, out);
}